// Round 2
// baseline (277.316 us; speedup 1.0000x reference)
//
#include <hip/hip_runtime.h>
#include <hip/hip_bf16.h>

#define NB 4       // batch
#define SEQ 1024
#define EMB 1024
#define NH 16
#define HD 64

typedef unsigned short u16;
typedef __attribute__((ext_vector_type(8))) __bf16 bf16x8;
typedef __attribute__((ext_vector_type(8))) short short8;
typedef __attribute__((ext_vector_type(4))) float floatx4;

// fp32 -> bf16 round-to-nearest-even
__device__ inline u16 f2b_rn(float f) {
    union { float f; unsigned int i; } x; x.f = f;
    unsigned int r = (x.i + 0x7FFFu + ((x.i >> 16) & 1u)) >> 16;
    return (u16)r;
}
__device__ inline bf16x8 s2b(short8 v) {
    union { short8 s; bf16x8 b; } x; x.s = v; return x.b;
}

// ---------------------------------------------------------------------------
// Kernel A: grid-stride fp32 -> bf16 conversion (n must be a multiple of 2048)
// ---------------------------------------------------------------------------
__global__ __launch_bounds__(256) void f32_to_b16(
    const float* __restrict__ src, u16* __restrict__ dst, int n)
{
    int i = (blockIdx.x * 256 + threadIdx.x) * 8;
    if (i + 8 <= n) {
        float4 a = *(const float4*)(src + i);
        float4 b = *(const float4*)(src + i + 4);
        union { u16 u[8]; int4 v; } o;
        o.u[0] = f2b_rn(a.x); o.u[1] = f2b_rn(a.y); o.u[2] = f2b_rn(a.z); o.u[3] = f2b_rn(a.w);
        o.u[4] = f2b_rn(b.x); o.u[5] = f2b_rn(b.y); o.u[6] = f2b_rn(b.z); o.u[7] = f2b_rn(b.w);
        *(int4*)(dst + i) = o.v;
    }
}

// ---------------------------------------------------------------------------
// Kernel 0: transpose+convert W[p][h][e][d] (fp32, H,E,HD) -> Wt[p][h][d][e] bf16
// ---------------------------------------------------------------------------
__global__ __launch_bounds__(256) void transpose_w(
    const float* __restrict__ Wq, const float* __restrict__ Wk, const float* __restrict__ Wv,
    u16* __restrict__ Wt)
{
    __shared__ u16 T[64 * 80];   // 64 rows (e) x 64 cols (d), stride 80
    int e0 = blockIdx.x * 64;
    int ph = blockIdx.y;
    int p = ph >> 4, h = ph & 15;
    const float* W = (p == 0 ? Wq : (p == 1 ? Wk : Wv)) + h * (EMB * HD);
    int tid = threadIdx.x;

    #pragma unroll
    for (int c = 0; c < 2; ++c) {
        int flat = c * 2048 + tid * 8;
        int r = flat >> 6;       // e_local
        int d = flat & 63;
        const float* s = W + (size_t)(e0 + r) * HD + d;
        float4 a = *(const float4*)(s);
        float4 b = *(const float4*)(s + 4);
        union { u16 u[8]; int4 v; } o;
        o.u[0] = f2b_rn(a.x); o.u[1] = f2b_rn(a.y); o.u[2] = f2b_rn(a.z); o.u[3] = f2b_rn(a.w);
        o.u[4] = f2b_rn(b.x); o.u[5] = f2b_rn(b.y); o.u[6] = f2b_rn(b.z); o.u[7] = f2b_rn(b.w);
        *(int4*)&T[r * 80 + d] = o.v;
    }
    __syncthreads();

    int d = tid >> 2;            // 0..63
    int ec = tid & 3;            // e-chunk of 16
    union { u16 u[16]; int4 v[2]; } tmp;
    #pragma unroll
    for (int i = 0; i < 16; ++i) tmp.u[i] = T[(ec * 16 + i) * 80 + d];
    u16* dst = Wt + ((size_t)(p * NH + h) * HD + d) * EMB + e0 + ec * 16;
    *(int4*)(dst) = tmp.v[0];
    *(int4*)(dst + 8) = tmp.v[1];
}

// ---------------------------------------------------------------------------
// Kernel 1: QKV projection GEMM (bf16 in, fp32 accum, bf16 out [b,h,s,d]).
// Block: 128 rows x 64 cols (one (p,h)), 256 threads = 4 waves, BK=32.
// ---------------------------------------------------------------------------
__global__ __launch_bounds__(256) void qkv_gemm(
    const u16* __restrict__ x,    // bf16 [4096][1024]
    const u16* __restrict__ Wt,   // bf16 [3][H][HD][E]
    const float* __restrict__ bq, const float* __restrict__ bk, const float* __restrict__ bv,
    u16* __restrict__ Q, u16* __restrict__ K, u16* __restrict__ V)  // each [B*H][S][HD]
{
    const int AP = 40;
    __shared__ u16 As[128 * AP];
    __shared__ u16 Bs[64 * AP];

    int m0 = blockIdx.x * 128;
    int ph = blockIdx.y;
    int p = ph >> 4, h = ph & 15;
    const u16* Bmat = Wt + (size_t)(p * NH + h) * HD * EMB;
    const float* bias = (p == 0 ? bq : (p == 1 ? bk : bv)) + h * HD;
    u16* Out = (p == 0 ? Q : (p == 1 ? K : V));

    int tid = threadIdx.x;
    int w = tid >> 6, lane = tid & 63, quad = lane >> 4, ln = lane & 15;

    floatx4 acc[2][4] = {};

    for (int k0 = 0; k0 < EMB; k0 += 32) {
        #pragma unroll
        for (int c = 0; c < 2; ++c) {
            int flat = c * 2048 + tid * 8;
            int r = flat >> 5, kk = flat & 31;
            *(int4*)&As[r * AP + kk] = *(const int4*)(x + (size_t)(m0 + r) * EMB + k0 + kk);
        }
        {
            int flat = tid * 8;
            int n = flat >> 5, kk = flat & 31;
            *(int4*)&Bs[n * AP + kk] = *(const int4*)(Bmat + (size_t)n * EMB + k0 + kk);
        }
        __syncthreads();

        bf16x8 b[4];
        #pragma unroll
        for (int nc = 0; nc < 4; ++nc)
            b[nc] = s2b(*(const short8*)&Bs[(nc * 16 + ln) * AP + quad * 8]);
        #pragma unroll
        for (int mt = 0; mt < 2; ++mt) {
            bf16x8 a = s2b(*(const short8*)&As[(w * 32 + mt * 16 + ln) * AP + quad * 8]);
            #pragma unroll
            for (int nc = 0; nc < 4; ++nc)
                acc[mt][nc] = __builtin_amdgcn_mfma_f32_16x16x32_bf16(a, b[nc], acc[mt][nc], 0, 0, 0);
        }
        __syncthreads();
    }

    #pragma unroll
    for (int nc = 0; nc < 4; ++nc) {
        int d = nc * 16 + ln;
        float bval = bias[d];
        #pragma unroll
        for (int mt = 0; mt < 2; ++mt) {
            #pragma unroll
            for (int reg = 0; reg < 4; ++reg) {
                int m = m0 + w * 32 + mt * 16 + quad * 4 + reg;
                int b_ = m >> 10, s = m & 1023;
                Out[((size_t)(b_ * NH + h) * SEQ + s) * HD + d] = f2b_rn(acc[mt][nc][reg] + bval);
            }
        }
    }
}

// ---------------------------------------------------------------------------
// Kernel 2: flash attention.  One block per (b,h, 64-row q-tile).
// ---------------------------------------------------------------------------
__global__ __launch_bounds__(256) void attn(
    const u16* __restrict__ Q, const u16* __restrict__ K, const u16* __restrict__ V,
    const int* __restrict__ mask,   // [B][S][S]
    u16* __restrict__ Aout)         // bf16 [B][S][E]
{
    const int P = 88;
    __shared__ u16 Qs[64 * P];
    __shared__ u16 Ks[64 * P];
    __shared__ u16 Vs[64 * P];
    __shared__ u16 Ps[64 * P];

    int q0 = blockIdx.x * 64;
    int bh = blockIdx.y;
    int b = bh >> 4, h = bh & 15;
    const u16* Qb = Q + (size_t)bh * SEQ * HD;
    const u16* Kb = K + (size_t)bh * SEQ * HD;
    const u16* Vb = V + (size_t)bh * SEQ * HD;
    const int* mrow = mask + (size_t)b * SEQ * SEQ;

    int tid = threadIdx.x;
    int w = tid >> 6, lane = tid & 63, quad = lane >> 4, ln = lane & 15;

    #pragma unroll
    for (int c = 0; c < 2; ++c) {
        int flat = c * 2048 + tid * 8;
        int r = flat >> 6, d = flat & 63;
        *(int4*)&Qs[r * P + d] = *(const int4*)(Qb + (size_t)(q0 + r) * HD + d);
    }

    float m_r[4], l_r[4];
    floatx4 o[4] = {};
    #pragma unroll
    for (int i = 0; i < 4; ++i) { m_r[i] = -INFINITY; l_r[i] = 0.f; }

    for (int tt = 0; tt < SEQ / 64; ++tt) {
        int t0 = tt * 64;
        __syncthreads();
        #pragma unroll
        for (int c = 0; c < 2; ++c) {
            int flat = c * 2048 + tid * 8;
            int r = flat >> 6, d = flat & 63;
            *(int4*)&Ks[r * P + d] = *(const int4*)(Kb + (size_t)(t0 + r) * HD + d);
            *(int4*)&Vs[r * P + d] = *(const int4*)(Vb + (size_t)(t0 + r) * HD + d);
        }
        __syncthreads();

        floatx4 sc[4] = {};
        #pragma unroll
        for (int kk = 0; kk < 64; kk += 32) {
            bf16x8 a = s2b(*(const short8*)&Qs[(w * 16 + ln) * P + kk + quad * 8]);
            #pragma unroll
            for (int nc = 0; nc < 4; ++nc) {
                bf16x8 bb = s2b(*(const short8*)&Ks[(nc * 16 + ln) * P + kk + quad * 8]);
                sc[nc] = __builtin_amdgcn_mfma_f32_16x16x32_bf16(a, bb, sc[nc], 0, 0, 0);
            }
        }

        #pragma unroll
        for (int nc = 0; nc < 4; ++nc) {
            int tcol = t0 + nc * 16 + ln;
            #pragma unroll
            for (int reg = 0; reg < 4; ++reg) {
                int srow = q0 + w * 16 + quad * 4 + reg;
                float v = sc[nc][reg] * 0.125f;
                if (mrow[(size_t)srow * SEQ + tcol] == 0) v = -1e30f;
                sc[nc][reg] = v;
            }
        }

        #pragma unroll
        for (int reg = 0; reg < 4; ++reg) {
            float mx = sc[0][reg];
            #pragma unroll
            for (int nc = 1; nc < 4; ++nc) mx = fmaxf(mx, sc[nc][reg]);
            #pragma unroll
            for (int off = 1; off < 16; off <<= 1) mx = fmaxf(mx, __shfl_xor(mx, off, 64));
            float mnew = fmaxf(m_r[reg], mx);
            float alpha = __expf(m_r[reg] - mnew);
            float rsum = 0.f;
            #pragma unroll
            for (int nc = 0; nc < 4; ++nc) {
                float pv = __expf(sc[nc][reg] - mnew);
                sc[nc][reg] = pv;
                rsum += pv;
            }
            #pragma unroll
            for (int off = 1; off < 16; off <<= 1) rsum += __shfl_xor(rsum, off, 64);
            l_r[reg] = l_r[reg] * alpha + rsum;
            m_r[reg] = mnew;
            #pragma unroll
            for (int dt = 0; dt < 4; ++dt) o[dt][reg] *= alpha;
        }

        #pragma unroll
        for (int nc = 0; nc < 4; ++nc)
            #pragma unroll
            for (int reg = 0; reg < 4; ++reg)
                Ps[(w * 16 + quad * 4 + reg) * P + nc * 16 + ln] = f2b_rn(sc[nc][reg]);

        __syncthreads();

        #pragma unroll
        for (int kk = 0; kk < 64; kk += 32) {
            bf16x8 a = s2b(*(const short8*)&Ps[(w * 16 + ln) * P + kk + quad * 8]);
            #pragma unroll
            for (int dt = 0; dt < 4; ++dt) {
                short8 bb;
                #pragma unroll
                for (int j = 0; j < 8; ++j)
                    bb[j] = (short)Vs[(kk + quad * 8 + j) * P + dt * 16 + ln];
                o[dt] = __builtin_amdgcn_mfma_f32_16x16x32_bf16(a, s2b(bb), o[dt], 0, 0, 0);
            }
        }
    }

    #pragma unroll
    for (int dt = 0; dt < 4; ++dt) {
        int d = dt * 16 + ln;
        #pragma unroll
        for (int reg = 0; reg < 4; ++reg) {
            int srow = q0 + w * 16 + quad * 4 + reg;
            float val = o[dt][reg] / l_r[reg];
            Aout[((size_t)b * SEQ + srow) * EMB + h * HD + d] = f2b_rn(val);
        }
    }
}

// ---------------------------------------------------------------------------
// Kernel 3: output projection.  Out[m,n] = A[m,:] @ Wo[n,:] + bo[n] (fp32 out).
// ---------------------------------------------------------------------------
__global__ __launch_bounds__(256) void out_proj(
    const u16* __restrict__ A,    // bf16 [4096][1024]
    const u16* __restrict__ Wo,   // bf16 [1024][1024] (n,k)
    const float* __restrict__ bo, // fp32 [1024]
    float* __restrict__ Out)      // fp32 [4096][1024]
{
    const int AP = 40;
    __shared__ u16 As[128 * AP];
    __shared__ u16 Bs[64 * AP];

    int m0 = blockIdx.x * 128;
    int n0 = blockIdx.y * 64;
    int tid = threadIdx.x;
    int w = tid >> 6, lane = tid & 63, quad = lane >> 4, ln = lane & 15;

    floatx4 acc[2][4] = {};

    for (int k0 = 0; k0 < EMB; k0 += 32) {
        #pragma unroll
        for (int c = 0; c < 2; ++c) {
            int flat = c * 2048 + tid * 8;
            int r = flat >> 5, kk = flat & 31;
            *(int4*)&As[r * AP + kk] = *(const int4*)(A + (size_t)(m0 + r) * EMB + k0 + kk);
        }
        {
            int flat = tid * 8;
            int n = flat >> 5, kk = flat & 31;
            *(int4*)&Bs[n * AP + kk] = *(const int4*)(Wo + (size_t)(n0 + n) * EMB + k0 + kk);
        }
        __syncthreads();

        bf16x8 b[4];
        #pragma unroll
        for (int nc = 0; nc < 4; ++nc)
            b[nc] = s2b(*(const short8*)&Bs[(nc * 16 + ln) * AP + quad * 8]);
        #pragma unroll
        for (int mt = 0; mt < 2; ++mt) {
            bf16x8 a = s2b(*(const short8*)&As[(w * 32 + mt * 16 + ln) * AP + quad * 8]);
            #pragma unroll
            for (int nc = 0; nc < 4; ++nc)
                acc[mt][nc] = __builtin_amdgcn_mfma_f32_16x16x32_bf16(a, b[nc], acc[mt][nc], 0, 0, 0);
        }
        __syncthreads();
    }

    #pragma unroll
    for (int nc = 0; nc < 4; ++nc) {
        int n = n0 + nc * 16 + ln;
        float bval = bo[n];
        #pragma unroll
        for (int mt = 0; mt < 2; ++mt) {
            #pragma unroll
            for (int reg = 0; reg < 4; ++reg) {
                int m = m0 + w * 32 + mt * 16 + quad * 4 + reg;
                Out[(size_t)m * EMB + n] = acc[mt][nc][reg] + bval;
            }
        }
    }
}

// ---------------------------------------------------------------------------
extern "C" void kernel_launch(void* const* d_in, const int* in_sizes, int n_in,
                              void* d_out, int out_size, void* d_ws, size_t ws_size,
                              hipStream_t stream) {
    const float* x  = (const float*)d_in[0];
    const int*   mk = (const int*)d_in[1];
    const float* Wq = (const float*)d_in[2];
    const float* bq = (const float*)d_in[3];
    const float* Wk = (const float*)d_in[4];
    const float* bk = (const float*)d_in[5];
    const float* Wv = (const float*)d_in[6];
    const float* bv = (const float*)d_in[7];
    const float* Wo = (const float*)d_in[8];
    const float* bo = (const float*)d_in[9];
    float* out = (float*)d_out;

    const int NX = NB * SEQ * EMB;     // 4,194,304
    const int NW = EMB * EMB;          // 1,048,576

    u16* xb  = (u16*)d_ws;                         // 8 MB
    u16* Wt  = xb + NX;                            // 6 MB  (3*NH*HD*EMB)
    u16* Qw  = Wt + 3 * NH * HD * EMB;             // 8 MB
    u16* Kw  = Qw + (size_t)NB * NH * SEQ * HD;    // 8 MB
    u16* Vw  = Kw + (size_t)NB * NH * SEQ * HD;    // 8 MB
    u16* Ao  = Vw + (size_t)NB * NH * SEQ * HD;    // 8 MB
    u16* Wob = Ao + (size_t)NB * SEQ * EMB;        // 2 MB   -> total 48 MB

    f32_to_b16<<<NX / 2048, 256, 0, stream>>>(x, xb, NX);
    f32_to_b16<<<NW / 2048, 256, 0, stream>>>(Wo, Wob, NW);
    transpose_w<<<dim3(EMB / 64, 3 * NH), 256, 0, stream>>>(Wq, Wk, Wv, Wt);
    qkv_gemm<<<dim3((NB * SEQ) / 128, 3 * NH), 256, 0, stream>>>(xb, Wt, bq, bk, bv, Qw, Kw, Vw);
    attn<<<dim3(SEQ / 64, NB * NH), 256, 0, stream>>>(Qw, Kw, Vw, mk, Ao);
    out_proj<<<dim3((NB * SEQ) / 128, EMB / 64), 256, 0, stream>>>(Ao, Wob, bo, out);
}

// Round 3
// 233.564 us; speedup vs baseline: 1.1873x; 1.1873x over previous
//
#include <hip/hip_runtime.h>
#include <hip/hip_bf16.h>

#define NB 4       // batch
#define SEQ 1024
#define EMB 1024
#define NH 16
#define HD 64

typedef unsigned short u16;
typedef __attribute__((ext_vector_type(8))) __bf16 bf16x8;
typedef __attribute__((ext_vector_type(8))) short short8;
typedef __attribute__((ext_vector_type(4))) float floatx4;

// fp32 -> bf16 round-to-nearest-even
__device__ inline u16 f2b_rn(float f) {
    union { float f; unsigned int i; } x; x.f = f;
    unsigned int r = (x.i + 0x7FFFu + ((x.i >> 16) & 1u)) >> 16;
    return (u16)r;
}
__device__ inline bf16x8 s2b(short8 v) {
    union { short8 s; bf16x8 b; } x; x.s = v; return x.b;
}

// async global->LDS, 16 B per lane.  LDS dest = wave-uniform base + lane*16.
__device__ inline void gload_lds16(const void* g, void* l) {
    __builtin_amdgcn_global_load_lds(
        (const __attribute__((address_space(1))) void*)g,
        (__attribute__((address_space(3))) void*)l, 16, 0, 0);
}

// XOR-swizzled fragment read from an unpadded [rows][64] u16 LDS buffer.
// Element (r,c) lives at r*64 + (c ^ ((r&7)*8)).  With fragment rows = x*16+ln
// this spreads 16 lanes' b128 reads across all banks (2-way alias only).
__device__ inline bf16x8 ldsfrag(const u16* base, int r, int c) {
    return s2b(*(const short8*)&base[r * 64 + (c ^ ((r & 7) * 8))]);
}

// ---------------------------------------------------------------------------
// Kernel A: grid-stride fp32 -> bf16 conversion (n multiple of 2048)
// ---------------------------------------------------------------------------
__global__ __launch_bounds__(256) void f32_to_b16(
    const float* __restrict__ src, u16* __restrict__ dst, int n)
{
    int i = (blockIdx.x * 256 + threadIdx.x) * 8;
    if (i + 8 <= n) {
        float4 a = *(const float4*)(src + i);
        float4 b = *(const float4*)(src + i + 4);
        union { u16 u[8]; int4 v; } o;
        o.u[0] = f2b_rn(a.x); o.u[1] = f2b_rn(a.y); o.u[2] = f2b_rn(a.z); o.u[3] = f2b_rn(a.w);
        o.u[4] = f2b_rn(b.x); o.u[5] = f2b_rn(b.y); o.u[6] = f2b_rn(b.z); o.u[7] = f2b_rn(b.w);
        *(int4*)(dst + i) = o.v;
    }
}

// ---------------------------------------------------------------------------
// Kernel B: mask -> per-(row, 64-col-tile) uint64 bitmask via wave ballot.
// bits[(b*SEQ + srow)*16 + tt], bit j = (mask[b][srow][tt*64+j] != 0)
// ---------------------------------------------------------------------------
__global__ __launch_bounds__(256) void mask_bits_k(
    const int* __restrict__ mask, unsigned long long* __restrict__ bits)
{
    int gw = blockIdx.x * 4 + (threadIdx.x >> 6);
    int lane = threadIdx.x & 63;
    int m = mask[(size_t)gw * 64 + lane];
    unsigned long long bl = __ballot(m != 0);
    if (lane == 0) bits[gw] = bl;
}

// ---------------------------------------------------------------------------
// Kernel 0: transpose+convert W[p][h][e][d] (fp32) -> Wt[p][h][d][e] bf16.
// Flattened, Wt is a [3072][1024] k-contiguous B matrix (n = p*1024+h*64+d).
// ---------------------------------------------------------------------------
__global__ __launch_bounds__(256) void transpose_w(
    const float* __restrict__ Wq, const float* __restrict__ Wk, const float* __restrict__ Wv,
    u16* __restrict__ Wt)
{
    __shared__ u16 T[64 * 80];
    int e0 = blockIdx.x * 64;
    int ph = blockIdx.y;
    int p = ph >> 4, h = ph & 15;
    const float* W = (p == 0 ? Wq : (p == 1 ? Wk : Wv)) + h * (EMB * HD);
    int tid = threadIdx.x;

    #pragma unroll
    for (int c = 0; c < 2; ++c) {
        int flat = c * 2048 + tid * 8;
        int r = flat >> 6;
        int d = flat & 63;
        const float* s = W + (size_t)(e0 + r) * HD + d;
        float4 a = *(const float4*)(s);
        float4 b = *(const float4*)(s + 4);
        union { u16 u[8]; int4 v; } o;
        o.u[0] = f2b_rn(a.x); o.u[1] = f2b_rn(a.y); o.u[2] = f2b_rn(a.z); o.u[3] = f2b_rn(a.w);
        o.u[4] = f2b_rn(b.x); o.u[5] = f2b_rn(b.y); o.u[6] = f2b_rn(b.z); o.u[7] = f2b_rn(b.w);
        *(int4*)&T[r * 80 + d] = o.v;
    }
    __syncthreads();

    int d = tid >> 2;
    int ec = tid & 3;
    union { u16 u[16]; int4 v[2]; } tmp;
    #pragma unroll
    for (int i = 0; i < 16; ++i) tmp.u[i] = T[(ec * 16 + i) * 80 + d];
    u16* dst = Wt + ((size_t)(p * NH + h) * HD + d) * EMB + e0 + ec * 16;
    *(int4*)(dst) = tmp.v[0];
    *(int4*)(dst + 8) = tmp.v[1];
}

// ---------------------------------------------------------------------------
// Kernel 1: fused QKV GEMM, m97 recipe.  C[4096][3072] = x @ Wt^T (+bias).
// 128x128 tile, 4 waves (2x2), BK=64, global_load_lds w=16, XOR swizzle.
// p==0 rows scaled by 0.125 (softmax scale folded in, exact).  V written
// transposed: Vt[b,h][d][s].
// ---------------------------------------------------------------------------
__global__ __launch_bounds__(256) void qkv_gemm(
    const u16* __restrict__ x,    // bf16 [4096][1024]
    const u16* __restrict__ Wt2,  // bf16 [3072][1024]
    const float* __restrict__ bq, const float* __restrict__ bk, const float* __restrict__ bv,
    u16* __restrict__ Q, u16* __restrict__ K, u16* __restrict__ Vt)
{
    __shared__ u16 As[128 * 64];
    __shared__ u16 Bs[128 * 64];

    int m0 = blockIdx.x * 128;
    int n0 = blockIdx.y * 128;
    int tid = threadIdx.x;
    int w = tid >> 6, lane = tid & 63, quad = lane >> 4, ln = lane & 15;
    int wm = w & 1, wn = w >> 1;

    floatx4 acc[4][4] = {};

    for (int k0 = 0; k0 < EMB; k0 += 64) {
        __syncthreads();
        #pragma unroll
        for (int i = 0; i < 4; ++i) {
            int flat0 = i * 256 + (tid & 192);     // wave-uniform chunk base
            int flat = flat0 + lane;
            int r = flat >> 3;
            int c = ((flat & 7) ^ (r & 7)) * 8;    // XOR swizzle
            gload_lds16(x   + (size_t)(m0 + r) * EMB + k0 + c, As + flat0 * 8);
            gload_lds16(Wt2 + (size_t)(n0 + r) * EMB + k0 + c, Bs + flat0 * 8);
        }
        __syncthreads();

        #pragma unroll
        for (int kk = 0; kk < 2; ++kk) {
            bf16x8 a[4], bf[4];
            #pragma unroll
            for (int mt = 0; mt < 4; ++mt)
                a[mt] = ldsfrag(As, wm * 64 + mt * 16 + ln, kk * 32 + quad * 8);
            #pragma unroll
            for (int nc = 0; nc < 4; ++nc)
                bf[nc] = ldsfrag(Bs, wn * 64 + nc * 16 + ln, kk * 32 + quad * 8);
            #pragma unroll
            for (int mt = 0; mt < 4; ++mt)
                #pragma unroll
                for (int nc = 0; nc < 4; ++nc)
                    acc[mt][nc] = __builtin_amdgcn_mfma_f32_16x16x32_bf16(a[mt], bf[nc], acc[mt][nc], 0, 0, 0);
        }
    }

    int p = n0 >> 10;   // uniform per block (1024 % 128 == 0)
    const float* bias = (p == 0 ? bq : (p == 1 ? bk : bv));
    if (p < 2) {
        u16* Out = (p == 0) ? Q : K;
        float qs = (p == 0) ? 0.125f : 1.0f;
        #pragma unroll
        for (int nc = 0; nc < 4; ++nc) {
            int n = n0 + wn * 64 + nc * 16 + ln;
            int h = (n >> 6) & 15, d = n & 63;
            float bv_ = bias[n & 1023];
            #pragma unroll
            for (int mt = 0; mt < 4; ++mt) {
                #pragma unroll
                for (int reg = 0; reg < 4; ++reg) {
                    int m = m0 + wm * 64 + mt * 16 + quad * 4 + reg;
                    int b_ = m >> 10, s = m & 1023;
                    Out[((size_t)(b_ * NH + h) * SEQ + s) * HD + d] = f2b_rn((acc[mt][nc][reg] + bv_) * qs);
                }
            }
        }
    } else {
        #pragma unroll
        for (int nc = 0; nc < 4; ++nc) {
            int n = n0 + wn * 64 + nc * 16 + ln;
            int h = (n >> 6) & 15, d = n & 63;
            float bv_ = bias[n & 1023];
            #pragma unroll
            for (int mt = 0; mt < 4; ++mt) {
                int m = m0 + wm * 64 + mt * 16 + quad * 4;   // 4 consecutive s
                int b_ = m >> 10, s = m & 1023;
                union { u16 u[4]; uint2 v; } pk;
                #pragma unroll
                for (int reg = 0; reg < 4; ++reg)
                    pk.u[reg] = f2b_rn(acc[mt][nc][reg] + bv_);
                *(uint2*)&Vt[((size_t)(b_ * NH + h) * HD + d) * SEQ + s] = pk.v;
            }
        }
    }
}

// ---------------------------------------------------------------------------
// Kernel 2: flash attention.  One block per (b,h, 64-row q-tile), 4 waves.
// Q fragments in registers; K,Vt staged via global_load_lds (swizzled);
// mask applied from the precomputed bitmask; Ps is per-wave (no barrier).
// ---------------------------------------------------------------------------
__global__ __launch_bounds__(256) void attn(
    const u16* __restrict__ Q, const u16* __restrict__ K, const u16* __restrict__ Vt,
    const unsigned long long* __restrict__ bits,
    u16* __restrict__ Aout)         // bf16 [B][S][E]
{
    const int PP = 72;  // Ps row stride (rows offset by 4 banks -> 2-way only)
    __shared__ u16 Ks[64 * 64];
    __shared__ u16 Vs[64 * 64];
    __shared__ u16 Ps[64 * PP];

    int q0 = blockIdx.x * 64;
    int bh = blockIdx.y;
    int b = bh >> 4, h = bh & 15;
    const u16* Qb = Q  + (size_t)bh * SEQ * HD;
    const u16* Kb = K  + (size_t)bh * SEQ * HD;
    const u16* Vb = Vt + (size_t)bh * HD * SEQ;   // [d][s]

    int tid = threadIdx.x;
    int w = tid >> 6, lane = tid & 63, quad = lane >> 4, ln = lane & 15;

    // Q fragment (A-operand) in registers, reused for all 16 t-tiles
    bf16x8 aq[2];
    {
        const u16* qp = Qb + (size_t)(q0 + w * 16 + ln) * HD + quad * 8;
        union { int4 i; bf16x8 b; } c0, c1;
        c0.i = *(const int4*)(qp);
        c1.i = *(const int4*)(qp + 32);
        aq[0] = c0.b; aq[1] = c1.b;
    }
    const unsigned long long* brow = bits + ((size_t)b * SEQ + q0 + w * 16 + quad * 4) * 16;

    float m_r[4], l_r[4];
    floatx4 o[4] = {};
    #pragma unroll
    for (int i = 0; i < 4; ++i) { m_r[i] = -INFINITY; l_r[i] = 0.f; }

    for (int tt = 0; tt < SEQ / 64; ++tt) {
        int t0 = tt * 64;
        __syncthreads();   // prev tile's LDS reads done
        #pragma unroll
        for (int i = 0; i < 2; ++i) {
            int flat0 = i * 256 + (tid & 192);
            int flat = flat0 + lane;
            int r = flat >> 3;
            int c = ((flat & 7) ^ (r & 7)) * 8;
            gload_lds16(Kb + (size_t)(t0 + r) * HD + c, Ks + flat0 * 8);      // K rows (t), cols d
            gload_lds16(Vb + (size_t)r * SEQ + t0 + c, Vs + flat0 * 8);       // Vt rows (d), cols t
        }
        __syncthreads();   // compiler drains vmcnt before s_barrier

        // S = Q K^T  (Q pre-scaled by 1/8)
        floatx4 sc[4] = {};
        #pragma unroll
        for (int kk = 0; kk < 2; ++kk)
            #pragma unroll
            for (int nc = 0; nc < 4; ++nc)
                sc[nc] = __builtin_amdgcn_mfma_f32_16x16x32_bf16(
                    aq[kk], ldsfrag(Ks, nc * 16 + ln, kk * 32 + quad * 8), sc[nc], 0, 0, 0);

        // mask via bitmask (usually skipped entirely)
        unsigned long long br[4];
        #pragma unroll
        for (int reg = 0; reg < 4; ++reg) br[reg] = brow[reg * 16 + tt];
        if (__any((br[0] & br[1] & br[2] & br[3]) != ~0ull)) {
            #pragma unroll
            for (int nc = 0; nc < 4; ++nc)
                #pragma unroll
                for (int reg = 0; reg < 4; ++reg)
                    if (!((br[reg] >> (nc * 16 + ln)) & 1)) sc[nc][reg] = -1e30f;
        }

        // online softmax (row = quad*4+reg, reduce across 16 lanes)
        #pragma unroll
        for (int reg = 0; reg < 4; ++reg) {
            float mx = fmaxf(fmaxf(sc[0][reg], sc[1][reg]), fmaxf(sc[2][reg], sc[3][reg]));
            #pragma unroll
            for (int off = 1; off < 16; off <<= 1) mx = fmaxf(mx, __shfl_xor(mx, off, 64));
            float mnew = fmaxf(m_r[reg], mx);
            float alpha = __expf(m_r[reg] - mnew);
            float rsum = 0.f;
            #pragma unroll
            for (int nc = 0; nc < 4; ++nc) {
                float pv = __expf(sc[nc][reg] - mnew);
                sc[nc][reg] = pv;
                rsum += pv;
            }
            #pragma unroll
            for (int off = 1; off < 16; off <<= 1) rsum += __shfl_xor(rsum, off, 64);
            l_r[reg] = l_r[reg] * alpha + rsum;
            m_r[reg] = mnew;
            #pragma unroll
            for (int dt = 0; dt < 4; ++dt) o[dt][reg] *= alpha;
        }

        // P -> LDS (per-wave region; no barrier needed between write & read)
        #pragma unroll
        for (int nc = 0; nc < 4; ++nc)
            #pragma unroll
            for (int reg = 0; reg < 4; ++reg)
                Ps[(w * 16 + quad * 4 + reg) * PP + nc * 16 + ln] = f2b_rn(sc[nc][reg]);

        // O += P V   (B-fragment from transposed V: vector reads)
        #pragma unroll
        for (int kk = 0; kk < 2; ++kk) {
            bf16x8 a = s2b(*(const short8*)&Ps[(w * 16 + ln) * PP + kk * 32 + quad * 8]);
            #pragma unroll
            for (int dt = 0; dt < 4; ++dt)
                o[dt] = __builtin_amdgcn_mfma_f32_16x16x32_bf16(
                    a, ldsfrag(Vs, dt * 16 + ln, kk * 32 + quad * 8), o[dt], 0, 0, 0);
        }
    }

    // epilogue: normalize, store bf16 [b][s][h*64+d]
    #pragma unroll
    for (int reg = 0; reg < 4; ++reg) {
        float inv = 1.0f / l_r[reg];
        int srow = q0 + w * 16 + quad * 4 + reg;
        #pragma unroll
        for (int dt = 0; dt < 4; ++dt) {
            int d = dt * 16 + ln;
            Aout[((size_t)b * SEQ + srow) * EMB + h * HD + d] = f2b_rn(o[dt][reg] * inv);
        }
    }
}

// ---------------------------------------------------------------------------
// Kernel 3: output projection, m97 recipe.  Out[4096][1024] fp32.
// ---------------------------------------------------------------------------
__global__ __launch_bounds__(256) void out_proj(
    const u16* __restrict__ A,    // bf16 [4096][1024]
    const u16* __restrict__ Wo,   // bf16 [1024][1024] (n,k)
    const float* __restrict__ bo,
    float* __restrict__ Out)
{
    __shared__ u16 As[128 * 64];
    __shared__ u16 Bs[128 * 64];

    int m0 = blockIdx.x * 128;
    int n0 = blockIdx.y * 128;
    int tid = threadIdx.x;
    int w = tid >> 6, lane = tid & 63, quad = lane >> 4, ln = lane & 15;
    int wm = w & 1, wn = w >> 1;

    floatx4 acc[4][4] = {};

    for (int k0 = 0; k0 < EMB; k0 += 64) {
        __syncthreads();
        #pragma unroll
        for (int i = 0; i < 4; ++i) {
            int flat0 = i * 256 + (tid & 192);
            int flat = flat0 + lane;
            int r = flat >> 3;
            int c = ((flat & 7) ^ (r & 7)) * 8;
            gload_lds16(A  + (size_t)(m0 + r) * EMB + k0 + c, As + flat0 * 8);
            gload_lds16(Wo + (size_t)(n0 + r) * EMB + k0 + c, Bs + flat0 * 8);
        }
        __syncthreads();

        #pragma unroll
        for (int kk = 0; kk < 2; ++kk) {
            bf16x8 a[4], bf[4];
            #pragma unroll
            for (int mt = 0; mt < 4; ++mt)
                a[mt] = ldsfrag(As, wm * 64 + mt * 16 + ln, kk * 32 + quad * 8);
            #pragma unroll
            for (int nc = 0; nc < 4; ++nc)
                bf[nc] = ldsfrag(Bs, wn * 64 + nc * 16 + ln, kk * 32 + quad * 8);
            #pragma unroll
            for (int mt = 0; mt < 4; ++mt)
                #pragma unroll
                for (int nc = 0; nc < 4; ++nc)
                    acc[mt][nc] = __builtin_amdgcn_mfma_f32_16x16x32_bf16(a[mt], bf[nc], acc[mt][nc], 0, 0, 0);
        }
    }

    #pragma unroll
    for (int nc = 0; nc < 4; ++nc) {
        int n = n0 + wn * 64 + nc * 16 + ln;
        float bb = bo[n];
        #pragma unroll
        for (int mt = 0; mt < 4; ++mt) {
            #pragma unroll
            for (int reg = 0; reg < 4; ++reg) {
                int m = m0 + wm * 64 + mt * 16 + quad * 4 + reg;
                Out[(size_t)m * EMB + n] = acc[mt][nc][reg] + bb;
            }
        }
    }
}

// ---------------------------------------------------------------------------
extern "C" void kernel_launch(void* const* d_in, const int* in_sizes, int n_in,
                              void* d_out, int out_size, void* d_ws, size_t ws_size,
                              hipStream_t stream) {
    const float* x  = (const float*)d_in[0];
    const int*   mk = (const int*)d_in[1];
    const float* Wq = (const float*)d_in[2];
    const float* bq = (const float*)d_in[3];
    const float* Wk = (const float*)d_in[4];
    const float* bk = (const float*)d_in[5];
    const float* Wv = (const float*)d_in[6];
    const float* bv = (const float*)d_in[7];
    const float* Wo = (const float*)d_in[8];
    const float* bo = (const float*)d_in[9];
    float* out = (float*)d_out;

    const int NX = NB * SEQ * EMB;     // 4,194,304
    const int NW = EMB * EMB;          // 1,048,576

    char* ws = (char*)d_ws;
    u16* xb  = (u16*)ws;                              // [ 0, 8M)
    u16* Wt  = (u16*)(ws + ((size_t)8  << 20));       // [ 8,14M)  (freed after qkv)
    u16* Wob = Wt;                                    //   alias [8,10M), used after qkv
    unsigned long long* bits = (unsigned long long*)(ws + ((size_t)10 << 20)); // [10,10.5M)
    u16* Qw  = (u16*)(ws + ((size_t)14 << 20));       // [14,22M)
    u16* Kw  = (u16*)(ws + ((size_t)22 << 20));       // [22,30M)
    u16* Vtw = (u16*)(ws + ((size_t)30 << 20));       // [30,38M)  transposed [b,h,d,s]
    u16* Ao  = (u16*)(ws + ((size_t)38 << 20));       // [38,46M)

    f32_to_b16<<<NX / 2048, 256, 0, stream>>>(x, xb, NX);
    transpose_w<<<dim3(EMB / 64, 3 * NH), 256, 0, stream>>>(Wq, Wk, Wv, Wt);
    qkv_gemm<<<dim3((NB * SEQ) / 128, 3 * EMB / 128), 256, 0, stream>>>(
        xb, Wt, bq, bk, bv, Qw, Kw, Vtw);
    // Wt consumed; now safe to overwrite its region with Wob / bits
    f32_to_b16<<<NW / 2048, 256, 0, stream>>>(Wo, Wob, NW);
    mask_bits_k<<<(NB * SEQ * 16) / 4, 256, 0, stream>>>(mk, bits);
    attn<<<dim3(SEQ / 64, NB * NH), 256, 0, stream>>>(Qw, Kw, Vtw, bits, Ao);
    out_proj<<<dim3((NB * SEQ) / 128, EMB / 128), 256, 0, stream>>>(Ao, Wob, bo, out);
}

// Round 5
// 207.665 us; speedup vs baseline: 1.3354x; 1.1247x over previous
//
#include <hip/hip_runtime.h>
#include <hip/hip_bf16.h>

#define NB 4       // batch
#define SEQ 1024
#define EMB 1024
#define NH 16
#define HD 64

typedef unsigned short u16;
typedef __attribute__((ext_vector_type(8))) __bf16 bf16x8;
typedef __attribute__((ext_vector_type(8))) short short8;
typedef __attribute__((ext_vector_type(4))) float floatx4;

// fp32 -> bf16 round-to-nearest-even
__device__ inline u16 f2b_rn(float f) {
    union { float f; unsigned int i; } x; x.f = f;
    unsigned int r = (x.i + 0x7FFFu + ((x.i >> 16) & 1u)) >> 16;
    return (u16)r;
}
__device__ inline bf16x8 s2b(short8 v) {
    union { short8 s; bf16x8 b; } x; x.s = v; return x.b;
}

// async global->LDS, 16 B per lane.  LDS dest = wave-uniform base + lane*16.
__device__ inline void gload_lds16(const void* g, void* l) {
    __builtin_amdgcn_global_load_lds(
        (const __attribute__((address_space(1))) void*)g,
        (__attribute__((address_space(3))) void*)l, 16, 0, 0);
}

// XOR-swizzled fragment read from an unpadded [rows][64] u16 LDS buffer.
__device__ inline bf16x8 ldsfrag(const u16* base, int r, int c) {
    return s2b(*(const short8*)&base[r * 64 + (c ^ ((r & 7) * 8))]);
}

__device__ inline void cvt8(const float* __restrict__ s, u16* __restrict__ d) {
    float4 a = *(const float4*)(s);
    float4 b = *(const float4*)(s + 4);
    union { u16 u[8]; int4 v; } o;
    o.u[0] = f2b_rn(a.x); o.u[1] = f2b_rn(a.y); o.u[2] = f2b_rn(a.z); o.u[3] = f2b_rn(a.w);
    o.u[4] = f2b_rn(b.x); o.u[5] = f2b_rn(b.y); o.u[6] = f2b_rn(b.z); o.u[7] = f2b_rn(b.w);
    *(int4*)(d) = o.v;
}

// ---------------------------------------------------------------------------
// Kernel P: fused prep.  blockIdx.x ranges:
//   [0,2048)      x fp32->bf16           (2048 elems/block)
//   [2048,2560)   Wo fp32->bf16
//   [2560,3328)   W transpose+convert -> Wt[3072][1024]
//   [3328,19712)  mask -> bitmask (4 wave-rows per block)
// ---------------------------------------------------------------------------
__global__ __launch_bounds__(256) void prep(
    const float* __restrict__ x, const float* __restrict__ Wq,
    const float* __restrict__ Wk, const float* __restrict__ Wv,
    const float* __restrict__ Wo, const int* __restrict__ mask,
    u16* __restrict__ xb, u16* __restrict__ Wt, u16* __restrict__ Wob,
    unsigned long long* __restrict__ bits)
{
    __shared__ u16 T[64 * 80];
    int bx = blockIdx.x;
    int tid = threadIdx.x;

    if (bx < 2048) {
        int i = bx * 2048 + tid * 8;
        cvt8(x + i, xb + i);
    } else if (bx < 2560) {
        int i = (bx - 2048) * 2048 + tid * 8;
        cvt8(Wo + i, Wob + i);
    } else if (bx < 3328) {
        int bx2 = bx - 2560;
        int e0 = (bx2 & 15) * 64;
        int ph = bx2 >> 4;              // 0..47
        int p = ph >> 4, h = ph & 15;
        const float* W = (p == 0 ? Wq : (p == 1 ? Wk : Wv)) + h * (EMB * HD);
        #pragma unroll
        for (int c = 0; c < 2; ++c) {
            int flat = c * 2048 + tid * 8;
            int r = flat >> 6;
            int d = flat & 63;
            cvt8(W + (size_t)(e0 + r) * HD + d, &T[r * 80 + d]);
        }
        __syncthreads();
        int d = tid >> 2;
        int ec = tid & 3;
        union { u16 u[16]; int4 v[2]; } tmp;
        #pragma unroll
        for (int i = 0; i < 16; ++i) tmp.u[i] = T[(ec * 16 + i) * 80 + d];
        u16* dst = Wt + ((size_t)(p * NH + h) * HD + d) * EMB + e0 + ec * 16;
        *(int4*)(dst) = tmp.v[0];
        *(int4*)(dst + 8) = tmp.v[1];
    } else {
        int gw = (bx - 3328) * 4 + (tid >> 6);   // 0..65535
        int lane = tid & 63;
        int m = mask[(size_t)gw * 64 + lane];
        unsigned long long bl = __ballot(m != 0);
        if (lane == 0) bits[gw] = bl;
    }
}

// ---------------------------------------------------------------------------
// Kernel 1: fused QKV GEMM, m97 recipe.  C[4096][3072] = x @ Wt^T (+bias).
// Q rows additionally scaled by log2(e)/8 (softmax scale + base-2 exp folded).
// V written transposed: Vt[b,h][d][s].
// ---------------------------------------------------------------------------
__global__ __launch_bounds__(256) void qkv_gemm(
    const u16* __restrict__ x,    // bf16 [4096][1024]
    const u16* __restrict__ Wt2,  // bf16 [3072][1024]
    const float* __restrict__ bq, const float* __restrict__ bk, const float* __restrict__ bv,
    u16* __restrict__ Q, u16* __restrict__ K, u16* __restrict__ Vt)
{
    __shared__ u16 As[128 * 64];
    __shared__ u16 Bs[128 * 64];

    int m0 = blockIdx.x * 128;
    int n0 = blockIdx.y * 128;
    int tid = threadIdx.x;
    int w = tid >> 6, lane = tid & 63, quad = lane >> 4, ln = lane & 15;
    int wm = w & 1, wn = w >> 1;

    floatx4 acc[4][4] = {};

    for (int k0 = 0; k0 < EMB; k0 += 64) {
        __syncthreads();
        #pragma unroll
        for (int i = 0; i < 4; ++i) {
            int flat0 = i * 256 + (tid & 192);
            int flat = flat0 + lane;
            int r = flat >> 3;
            int c = ((flat & 7) ^ (r & 7)) * 8;
            gload_lds16(x   + (size_t)(m0 + r) * EMB + k0 + c, As + flat0 * 8);
            gload_lds16(Wt2 + (size_t)(n0 + r) * EMB + k0 + c, Bs + flat0 * 8);
        }
        __syncthreads();

        #pragma unroll
        for (int kk = 0; kk < 2; ++kk) {
            bf16x8 a[4], bf[4];
            #pragma unroll
            for (int mt = 0; mt < 4; ++mt)
                a[mt] = ldsfrag(As, wm * 64 + mt * 16 + ln, kk * 32 + quad * 8);
            #pragma unroll
            for (int nc = 0; nc < 4; ++nc)
                bf[nc] = ldsfrag(Bs, wn * 64 + nc * 16 + ln, kk * 32 + quad * 8);
            #pragma unroll
            for (int mt = 0; mt < 4; ++mt)
                #pragma unroll
                for (int nc = 0; nc < 4; ++nc)
                    acc[mt][nc] = __builtin_amdgcn_mfma_f32_16x16x32_bf16(a[mt], bf[nc], acc[mt][nc], 0, 0, 0);
        }
    }

    int p = n0 >> 10;
    const float* bias = (p == 0 ? bq : (p == 1 ? bk : bv));
    if (p < 2) {
        u16* Out = (p == 0) ? Q : K;
        float qs = (p == 0) ? 0.125f * 1.44269504f : 1.0f;   // fold 1/sqrt(64) and log2(e)
        #pragma unroll
        for (int nc = 0; nc < 4; ++nc) {
            int n = n0 + wn * 64 + nc * 16 + ln;
            int h = (n >> 6) & 15, d = n & 63;
            float bv_ = bias[n & 1023];
            #pragma unroll
            for (int mt = 0; mt < 4; ++mt) {
                #pragma unroll
                for (int reg = 0; reg < 4; ++reg) {
                    int m = m0 + wm * 64 + mt * 16 + quad * 4 + reg;
                    int b_ = m >> 10, s = m & 1023;
                    Out[((size_t)(b_ * NH + h) * SEQ + s) * HD + d] = f2b_rn((acc[mt][nc][reg] + bv_) * qs);
                }
            }
        }
    } else {
        #pragma unroll
        for (int nc = 0; nc < 4; ++nc) {
            int n = n0 + wn * 64 + nc * 16 + ln;
            int h = (n >> 6) & 15, d = n & 63;
            float bv_ = bias[n & 1023];
            #pragma unroll
            for (int mt = 0; mt < 4; ++mt) {
                int m = m0 + wm * 64 + mt * 16 + quad * 4;
                int b_ = m >> 10, s = m & 1023;
                union { u16 u[4]; uint2 v; } pk;
                #pragma unroll
                for (int reg = 0; reg < 4; ++reg)
                    pk.u[reg] = f2b_rn(acc[mt][nc][reg] + bv_);
                *(uint2*)&Vt[((size_t)(b_ * NH + h) * HD + d) * SEQ + s] = pk.v;
            }
        }
    }
}

// ---------------------------------------------------------------------------
// Kernel 2: flash attention v3.  Block = 128 threads = 2 waves; one block per
// (b,h, 64-row q-tile).  Wave owns 2 strips of 16 q-rows.  S computed
// TRANSPOSED (S^T = K Q^T) so each lane owns one softmax column (m = ln):
// in-lane reductions, contiguous packed P writes.  No online max: Q carries
// log2e/8, P = exp2(s); l comes free from a ones-row appended to V.
// ---------------------------------------------------------------------------
__global__ __launch_bounds__(128) void attn(
    const u16* __restrict__ Q, const u16* __restrict__ K, const u16* __restrict__ Vt,
    const unsigned long long* __restrict__ bits,
    u16* __restrict__ Aout)         // bf16 [B][S][E]
{
    const int PP = 72;  // Ps row stride in u16 (144 B)
    __shared__ u16 Ks[64 * 64];
    __shared__ u16 Vs[80 * 64];     // rows 0..63 = V^T tile, row 64 = ones, 65..79 unused
    __shared__ u16 Ps[64 * PP];

    int q0 = blockIdx.x * 64;
    int bh = blockIdx.y;
    int b = bh >> 4, h = bh & 15;
    const u16* Qb = Q  + (size_t)bh * SEQ * HD;
    const u16* Kb = K  + (size_t)bh * SEQ * HD;
    const u16* Vb = Vt + (size_t)bh * HD * SEQ;   // [d][s]

    int tid = threadIdx.x;
    int w = tid >> 6, lane = tid & 63, quad = lane >> 4, ln = lane & 15;

    // ones row (d = 64) for the l-column trick
    if (tid < 16) *(uint2*)&Vs[64 * 64 + tid * 4] = make_uint2(0x3F803F80u, 0x3F803F80u);

    // Q B-fragments (output-col = m), one per strip per kk, reused all tiles
    bf16x8 qf[2][2];
    #pragma unroll
    for (int s = 0; s < 2; ++s) {
        const u16* qp = Qb + (size_t)(q0 + w * 32 + s * 16 + ln) * HD + quad * 8;
        union { int4 i; bf16x8 b; } c0, c1;
        c0.i = *(const int4*)(qp);
        c1.i = *(const int4*)(qp + 32);
        qf[s][0] = c0.b; qf[s][1] = c1.b;
    }

    floatx4 o[2][5] = {};   // [strip][dt], dt=4 is the l column

    for (int tt = 0; tt < SEQ / 64; ++tt) {
        int t0 = tt * 64;
        __syncthreads();
        #pragma unroll
        for (int i = 0; i < 4; ++i) {
            int flat0 = i * 128 + (tid & 64);
            int flat = flat0 + lane;
            int r = flat >> 3;
            int c = ((flat & 7) ^ (r & 7)) * 8;
            gload_lds16(Kb + (size_t)(t0 + r) * HD + c, Ks + flat0 * 8);
            gload_lds16(Vb + (size_t)r * SEQ + t0 + c, Vs + flat0 * 8);
        }
        __syncthreads();

        // S^T = K Q^T : rows t, cols m
        floatx4 sc[2][4] = {};
        #pragma unroll
        for (int kk = 0; kk < 2; ++kk) {
            bf16x8 kf[4];
            #pragma unroll
            for (int tb = 0; tb < 4; ++tb)
                kf[tb] = ldsfrag(Ks, tb * 16 + ln, kk * 32 + quad * 8);
            #pragma unroll
            for (int s = 0; s < 2; ++s)
                #pragma unroll
                for (int tb = 0; tb < 4; ++tb)
                    sc[s][tb] = __builtin_amdgcn_mfma_f32_16x16x32_bf16(kf[tb], qf[s][kk], sc[s][tb], 0, 0, 0);
        }

        // mask (bit j of bm = col t0+j valid), lane's softmax column m = ln
        #pragma unroll
        for (int s = 0; s < 2; ++s) {
            unsigned long long bm = bits[((size_t)b * SEQ + q0 + w * 32 + s * 16 + ln) * 16 + tt];
            if (__any(bm != ~0ull)) {
                #pragma unroll
                for (int tb = 0; tb < 4; ++tb)
                    #pragma unroll
                    for (int reg = 0; reg < 4; ++reg)
                        if (!((bm >> (tb * 16 + quad * 4 + reg)) & 1)) sc[s][tb][reg] = -1e30f;
            }
        }

        // P = exp2(S), pack 4 consecutive t (regs) -> b64 LDS write
        #pragma unroll
        for (int s = 0; s < 2; ++s) {
            int mrow = w * 32 + s * 16 + ln;
            #pragma unroll
            for (int tb = 0; tb < 4; ++tb) {
                union { float f; unsigned int i; } e0_, e1_, e2_, e3_;
                e0_.f = __builtin_amdgcn_exp2f(sc[s][tb][0]);
                e1_.f = __builtin_amdgcn_exp2f(sc[s][tb][1]);
                e2_.f = __builtin_amdgcn_exp2f(sc[s][tb][2]);
                e3_.f = __builtin_amdgcn_exp2f(sc[s][tb][3]);
                uint2 pk;
                pk.x = ((e0_.i + 0x8000u) >> 16) | ((e1_.i + 0x8000u) & 0xFFFF0000u);
                pk.y = ((e2_.i + 0x8000u) >> 16) | ((e3_.i + 0x8000u) & 0xFFFF0000u);
                *(uint2*)&Ps[mrow * PP + tb * 16 + quad * 4] = pk;
            }
        }

        // O += P V  (and l accumulates in dt=4 via the ones row)
        #pragma unroll
        for (int kk = 0; kk < 2; ++kk) {
            bf16x8 vf[5];
            #pragma unroll
            for (int dt = 0; dt < 5; ++dt)
                vf[dt] = ldsfrag(Vs, dt * 16 + ln, kk * 32 + quad * 8);
            #pragma unroll
            for (int s = 0; s < 2; ++s) {
                bf16x8 pf = s2b(*(const short8*)&Ps[(w * 32 + s * 16 + ln) * PP + kk * 32 + quad * 8]);
                #pragma unroll
                for (int dt = 0; dt < 5; ++dt)
                    o[s][dt] = __builtin_amdgcn_mfma_f32_16x16x32_bf16(pf, vf[dt], o[s][dt], 0, 0, 0);
            }
        }
    }

    // epilogue: l lives in o[s][4] column 64 (lane ln==0 of each quad)
    #pragma unroll
    for (int s = 0; s < 2; ++s) {
        #pragma unroll
        for (int reg = 0; reg < 4; ++reg) {
            float l = __shfl(o[s][4][reg], lane & 48, 64);
            float inv = 1.0f / l;
            int m = q0 + w * 32 + s * 16 + quad * 4 + reg;
            #pragma unroll
            for (int dt = 0; dt < 4; ++dt)
                Aout[((size_t)b * SEQ + m) * EMB + h * HD + dt * 16 + ln] = f2b_rn(o[s][dt][reg] * inv);
        }
    }
}

// ---------------------------------------------------------------------------
// Kernel 3: output projection, m97 recipe.  Out[4096][1024] fp32.
// ---------------------------------------------------------------------------
__global__ __launch_bounds__(256) void out_proj(
    const u16* __restrict__ A,    // bf16 [4096][1024]
    const u16* __restrict__ Wo,   // bf16 [1024][1024] (n,k)
    const float* __restrict__ bo,
    float* __restrict__ Out)
{
    __shared__ u16 As[128 * 64];
    __shared__ u16 Bs[128 * 64];

    int m0 = blockIdx.x * 128;
    int n0 = blockIdx.y * 128;
    int tid = threadIdx.x;
    int w = tid >> 6, lane = tid & 63, quad = lane >> 4, ln = lane & 15;
    int wm = w & 1, wn = w >> 1;

    floatx4 acc[4][4] = {};

    for (int k0 = 0; k0 < EMB; k0 += 64) {
        __syncthreads();
        #pragma unroll
        for (int i = 0; i < 4; ++i) {
            int flat0 = i * 256 + (tid & 192);
            int flat = flat0 + lane;
            int r = flat >> 3;
            int c = ((flat & 7) ^ (r & 7)) * 8;
            gload_lds16(A  + (size_t)(m0 + r) * EMB + k0 + c, As + flat0 * 8);
            gload_lds16(Wo + (size_t)(n0 + r) * EMB + k0 + c, Bs + flat0 * 8);
        }
        __syncthreads();

        #pragma unroll
        for (int kk = 0; kk < 2; ++kk) {
            bf16x8 a[4], bf[4];
            #pragma unroll
            for (int mt = 0; mt < 4; ++mt)
                a[mt] = ldsfrag(As, wm * 64 + mt * 16 + ln, kk * 32 + quad * 8);
            #pragma unroll
            for (int nc = 0; nc < 4; ++nc)
                bf[nc] = ldsfrag(Bs, wn * 64 + nc * 16 + ln, kk * 32 + quad * 8);
            #pragma unroll
            for (int mt = 0; mt < 4; ++mt)
                #pragma unroll
                for (int nc = 0; nc < 4; ++nc)
                    acc[mt][nc] = __builtin_amdgcn_mfma_f32_16x16x32_bf16(a[mt], bf[nc], acc[mt][nc], 0, 0, 0);
        }
    }

    #pragma unroll
    for (int nc = 0; nc < 4; ++nc) {
        int n = n0 + wn * 64 + nc * 16 + ln;
        float bb = bo[n];
        #pragma unroll
        for (int mt = 0; mt < 4; ++mt) {
            #pragma unroll
            for (int reg = 0; reg < 4; ++reg) {
                int m = m0 + wm * 64 + mt * 16 + quad * 4 + reg;
                Out[(size_t)m * EMB + n] = acc[mt][nc][reg] + bb;
            }
        }
    }
}

// ---------------------------------------------------------------------------
extern "C" void kernel_launch(void* const* d_in, const int* in_sizes, int n_in,
                              void* d_out, int out_size, void* d_ws, size_t ws_size,
                              hipStream_t stream) {
    const float* x  = (const float*)d_in[0];
    const int*   mk = (const int*)d_in[1];
    const float* Wq = (const float*)d_in[2];
    const float* bq = (const float*)d_in[3];
    const float* Wk = (const float*)d_in[4];
    const float* bk = (const float*)d_in[5];
    const float* Wv = (const float*)d_in[6];
    const float* bv = (const float*)d_in[7];
    const float* Wo = (const float*)d_in[8];
    const float* bo = (const float*)d_in[9];
    float* out = (float*)d_out;

    const size_t MB = 1u << 20;
    char* ws = (char*)d_ws;
    u16* xb  = (u16*)ws;                                   // [ 0, 8M)
    u16* Wt  = (u16*)(ws + 8 * MB);                        // [ 8,14M)
    u16* Wob = (u16*)(ws + 14 * MB);                       // [14,16M)
    unsigned long long* bits = (unsigned long long*)(ws + 16 * MB); // [16,16.5M)
    u16* Qw  = (u16*)(ws + 16 * MB + 512 * 1024);          // [16.5,24.5M)
    u16* Kw  = (u16*)(ws + 24 * MB + 512 * 1024);          // [24.5,32.5M)
    u16* Vtw = (u16*)(ws + 32 * MB + 512 * 1024);          // [32.5,40.5M)
    u16* Ao  = xb;                                         // reuse: xb dead after qkv

    prep<<<19712, 256, 0, stream>>>(x, Wq, Wk, Wv, Wo, mk, xb, Wt, Wob, bits);
    qkv_gemm<<<dim3((NB * SEQ) / 128, 3 * EMB / 128), 256, 0, stream>>>(
        xb, Wt, bq, bk, bv, Qw, Kw, Vtw);
    attn<<<dim3(SEQ / 64, NB * NH), 128, 0, stream>>>(Qw, Kw, Vtw, bits, Ao);
    out_proj<<<dim3((NB * SEQ) / 128, EMB / 128), 256, 0, stream>>>(Ao, Wob, bo, out);
}